// Round 3
// baseline (186.098 us; speedup 1.0000x reference)
//
#include <hip/hip_runtime.h>
#include <hip/hip_bf16.h>

#define NPIX (8*128*128)   // 131072 pixels
#define CH   256

typedef __attribute__((ext_vector_type(8))) short bf16x8;
typedef __attribute__((ext_vector_type(4))) float f32x4;

// pair convert f32x2 -> packed bf16x2 (compiler emits v_cvt_pk_bf16_f32)
__device__ inline unsigned int pkbf(float a, float b) {
    union { __hip_bfloat162 h; unsigned int u; } c;
    c.h = __float22bfloat162_rn(float2{a, b});
    return c.u;
}
__device__ inline unsigned short f2bf(float f) {
    unsigned int u = __float_as_uint(f);
    return (unsigned short)((u + 0x7FFFu + ((u >> 16) & 1u)) >> 16);  // RNE
}

// Fully fused SIREN: 12 -> 256 (fp32 VALU) -> 256 (bf16 MFMA) -> 3 (bf16 MFMA)
// out = z + 0.5*sin(30*(...)).  Single kernel, 64 pixels/block, 4 waves.
// h [64 pix][256 ch] bf16 in LDS (32 KB), XOR-swizzled byte ^= (pix&31)<<4;
// holds h1, then reused for h2 after a barrier.  4 blocks/CU resident.
__global__ __launch_bounds__(256, 4) void rendernet_fused(
    const float* __restrict__ z,
    const float* __restrict__ nrm,
    const float* __restrict__ sph,
    const float* __restrict__ pc,
    const float* __restrict__ vd,
    const float* __restrict__ W1,
    const float* __restrict__ b1,
    const float* __restrict__ W2,
    const float* __restrict__ b2,
    const float* __restrict__ W4,
    const float* __restrict__ b4,
    float* __restrict__ out)
{
    __shared__ __align__(16) char smem[64 * 512];   // 32 KB

    const int tid     = threadIdx.x;
    const int lane    = tid & 63;
    const int wave    = tid >> 6;
    const int pixbase = blockIdx.x * 64;

    // ---------------- layer 1 (fp32): thread = (pixel=lane, 64-ch chunk=wave) ----------------
    {
        const int p   = lane;
        const int c0  = wave * 64;               // wave-uniform -> scalar W1/b1 loads
        const int gp  = pixbase + p;
        const int swz = (p & 31) << 4;

        float xv[12];
        #pragma unroll
        for (int k = 0; k < 3; ++k) xv[k]     = sph[k*NPIX + gp];
        #pragma unroll
        for (int k = 0; k < 3; ++k) xv[3 + k] = nrm[k*NPIX + gp];
        #pragma unroll
        for (int k = 0; k < 3; ++k) xv[6 + k] = pc [k*NPIX + gp];
        #pragma unroll
        for (int k = 0; k < 3; ++k) xv[9 + k] = vd [k*NPIX + gp];

        #pragma unroll
        for (int cc = 0; cc < 64; cc += 8) {
            float hv[8];
            #pragma unroll
            for (int u = 0; u < 8; ++u) {
                const int c = c0 + cc + u;
                float a = b1[c];
                #pragma unroll
                for (int k = 0; k < 12; ++k) a += W1[c*12 + k] * xv[k];
                hv[u] = __sinf(30.0f * a);
            }
            union { unsigned int w[4]; bf16x8 v; } t;
            #pragma unroll
            for (int u = 0; u < 4; ++u) t.w[u] = pkbf(hv[2*u], hv[2*u + 1]);
            *(bf16x8*)(smem + p*512 + (((c0 + cc)*2) ^ swz)) = t.v;
        }
    }
    __syncthreads();

    // ---------------- layer 2 (bf16 MFMA): wave = 64 pix x 64 out-ch, K=256 ----------------
    const int lm = lane & 15;     // A row / B,D col
    const int lg = lane >> 4;     // k-group of 8 / D row-group of 4
    const int n0 = wave * 64;

    f32x4 acc[4][4];
    #pragma unroll
    for (int i = 0; i < 4; ++i)
        #pragma unroll
        for (int j = 0; j < 4; ++j) acc[i][j] = (f32x4){0.f, 0.f, 0.f, 0.f};

    const float* wp = W2 + (n0 + lm)*CH + lg*8;

    #pragma unroll
    for (int k0 = 0; k0 < CH; k0 += 32) {
        bf16x8 afr[4];
        #pragma unroll
        for (int mf = 0; mf < 4; ++mf) {
            const int pr = mf*16 + lm;
            afr[mf] = *(const bf16x8*)(smem + pr*512 + (((k0 + lg*8)*2) ^ ((pr & 31) << 4)));
        }
        #pragma unroll
        for (int nf = 0; nf < 4; ++nf) {
            f32x4 lo = *(const f32x4*)(wp + nf*16*CH + k0);
            f32x4 hi = *(const f32x4*)(wp + nf*16*CH + k0 + 4);
            union { unsigned int w[4]; bf16x8 v; } t;
            t.w[0] = pkbf(lo[0], lo[1]);  t.w[1] = pkbf(lo[2], lo[3]);
            t.w[2] = pkbf(hi[0], hi[1]);  t.w[3] = pkbf(hi[2], hi[3]);
            #pragma unroll
            for (int mf = 0; mf < 4; ++mf)
                acc[mf][nf] = __builtin_amdgcn_mfma_f32_16x16x32_bf16(
                                  afr[mf], t.v, acc[mf][nf], 0, 0, 0);
        }
    }
    __syncthreads();   // all h1 reads done

    // ---------------- layer 2 epilogue: h2 = sin(30*(acc+b2)) -> bf16 LDS (same buffer) ----
    {
        float b2v[4];
        #pragma unroll
        for (int nf = 0; nf < 4; ++nf) b2v[nf] = b2[n0 + nf*16 + lm];

        #pragma unroll
        for (int mf = 0; mf < 4; ++mf)
            #pragma unroll
            for (int nf = 0; nf < 4; ++nf)
                #pragma unroll
                for (int r = 0; r < 4; ++r) {
                    const int pix = mf*16 + lg*4 + r;          // D row = pixel
                    const int ch  = n0 + nf*16 + lm;           // D col = out-ch
                    const unsigned short hv =
                        f2bf(__sinf(30.0f * (acc[mf][nf][r] + b2v[nf])));
                    *(unsigned short*)(smem + pix*512 + ((ch*2) ^ ((pix & 31) << 4))) = hv;
                }
    }
    __syncthreads();

    // ---------------- layer 4 (bf16 MFMA, wave 0 only; waves 1-3 exit) ----------------
    // A = h2 [64 pix][256], B = W4^T [256][3 (cols 3..15 garbage, owned by idle lanes)]
    if (wave == 0) {
        f32x4 d[4];
        #pragma unroll
        for (int i = 0; i < 4; ++i) d[i] = (f32x4){0.f, 0.f, 0.f, 0.f};

        const int   c3  = (lm < 3) ? lm : 2;        // clamp: valid memory, garbage ok
        const float* w4p = W4 + c3*CH + lg*8;

        #pragma unroll
        for (int k0 = 0; k0 < CH; k0 += 32) {
            bf16x8 afr[4];
            #pragma unroll
            for (int mf = 0; mf < 4; ++mf) {
                const int pr = mf*16 + lm;
                afr[mf] = *(const bf16x8*)(smem + pr*512 + (((k0 + lg*8)*2) ^ ((pr & 31) << 4)));
            }
            f32x4 lo = *(const f32x4*)(w4p + k0);
            f32x4 hi = *(const f32x4*)(w4p + k0 + 4);
            union { unsigned int w[4]; bf16x8 v; } t;
            t.w[0] = pkbf(lo[0], lo[1]);  t.w[1] = pkbf(lo[2], lo[3]);
            t.w[2] = pkbf(hi[0], hi[1]);  t.w[3] = pkbf(hi[2], hi[3]);
            #pragma unroll
            for (int mf = 0; mf < 4; ++mf)
                d[mf] = __builtin_amdgcn_mfma_f32_16x16x32_bf16(afr[mf], t.v, d[mf], 0, 0, 0);
        }

        if (lm < 3) {
            const float b4v = b4[lm];
            #pragma unroll
            for (int mf = 0; mf < 4; ++mf)
                #pragma unroll
                for (int r = 0; r < 4; ++r) {
                    const int pix = mf*16 + lg*4 + r;
                    const int gi  = lm*NPIX + pixbase + pix;
                    out[gi] = z[gi] + 0.5f * __sinf(30.0f * (d[mf][r] + b4v));
                }
        }
    }
}

extern "C" void kernel_launch(void* const* d_in, const int* in_sizes, int n_in,
                              void* d_out, int out_size, void* d_ws, size_t ws_size,
                              hipStream_t stream) {
    const float* z   = (const float*)d_in[0];
    const float* nrm = (const float*)d_in[1];
    // d_in[2] = ad : unused by the reference
    const float* s   = (const float*)d_in[3];
    const float* pc  = (const float*)d_in[4];
    const float* vd  = (const float*)d_in[5];
    const float* W1  = (const float*)d_in[6];
    const float* b1  = (const float*)d_in[7];
    const float* W2  = (const float*)d_in[8];
    const float* b2  = (const float*)d_in[9];
    const float* W4  = (const float*)d_in[10];
    const float* b4  = (const float*)d_in[11];
    float* out = (float*)d_out;

    rendernet_fused<<<dim3(NPIX / 64), dim3(256), 0, stream>>>(
        z, nrm, s, pc, vd, W1, b1, W2, b2, W4, b4, out);
}